// Round 8
// baseline (141.844 us; speedup 1.0000x reference)
//
#include <hip/hip_runtime.h>
#include <stdint.h>

// Z9QATAttention: out = softmax_causal((x@Wqkv).q @ (x@Wqkv).k^T * D^-0.5) @ v @ Wout
// charge_bias: uniform pre-mask logit shift -> softmax-invariant -> no-op.
// mask == tril -> causal predicate. Softmax scale*log2e folded into q columns in GEMM1.
// Round 8: GEMMs get counted-vmcnt depth-2 staging (triple-buffer); attn unchanged.

typedef __attribute__((ext_vector_type(4))) float f32x4;
typedef __attribute__((ext_vector_type(16))) float f32x16;
typedef __attribute__((ext_vector_type(8))) __bf16 bf16x8;
typedef __attribute__((ext_vector_type(8))) unsigned short ushort8;
typedef __attribute__((ext_vector_type(4))) unsigned short ushort4v;
typedef __attribute__((ext_vector_type(4))) unsigned int uint4v;

#define DEV __device__ __forceinline__

DEV unsigned short f32_to_bf16(float f) {
    union { float f; unsigned int u; } cv; cv.f = f;
    unsigned int u = cv.u;
    return (unsigned short)((u + 0x7FFFu + ((u >> 16) & 1u)) >> 16);
}

DEV float bf16_to_f32(unsigned short u) {
    union { unsigned int i; float f; } cv; cv.i = ((unsigned int)u) << 16;
    return cv.f;
}

DEV bf16x8 load_bf16x8(const unsigned short* p) {
    ushort8 v = *(const ushort8*)p;
    return __builtin_bit_cast(bf16x8, v);
}

DEV unsigned cvt_pk_bf16(float lo, float hi) {
    unsigned r;
    asm("v_cvt_pk_bf16_f32 %0, %1, %2" : "=v"(r) : "v"(lo), "v"(hi));
    return r;
}

DEV void gload_lds16(const void* g, void* l) {
    __builtin_amdgcn_global_load_lds(
        (const __attribute__((address_space(1))) unsigned int*)g,
        (__attribute__((address_space(3))) unsigned int*)l, 16, 0, 0);
}

DEV f32x16 vzero16() {
    f32x16 v;
#pragma unroll
    for (int i = 0; i < 16; ++i) v[i] = 0.f;
    return v;
}

// tree reductions over the 32 S values (depth 5 instead of 31-deep chains)
DEV float tmax32(const f32x16& a, const f32x16& b) {
    float m[16];
#pragma unroll
    for (int i = 0; i < 16; ++i) m[i] = fmaxf(a[i], b[i]);
#pragma unroll
    for (int st = 8; st > 0; st >>= 1)
#pragma unroll
        for (int i = 0; i < 8; ++i) if (i < st) m[i] = fmaxf(m[i], m[i + st]);
    return m[0];
}
DEV float tsum32(const f32x16& a, const f32x16& b) {
    float m[16];
#pragma unroll
    for (int i = 0; i < 16; ++i) m[i] = a[i] + b[i];
#pragma unroll
    for (int st = 8; st > 0; st >>= 1)
#pragma unroll
        for (int i = 0; i < 8; ++i) if (i < st) m[i] = m[i] + m[i + st];
    return m[0];
}

// LPT work table: 24 items per (b,h), j-major dispatch so heaviest run first.
// qtab = q-tile index; ctab: 255 = full q-tile, 0 = kv chunk [0,q+1), 1 = chunk [q+1,2q+2).
__device__ __constant__ unsigned char qtab[24] = {15,15,7,14,14,13,13,6,12,12,11,11,5,10,10,9,9,4,8,8,3,2,1,0};
__device__ __constant__ unsigned char ctab[24] = {0,1,255,0,1,0,1,255,0,1,0,1,255,0,1,0,1,255,0,1,255,255,255,255};

// ---------------- fp32 -> bf16 conversion (8 elems/thread) ----------------
__global__ void cvt_kernel(const float* __restrict__ in, unsigned short* __restrict__ out, int n) {
    int i = (blockIdx.x * blockDim.x + threadIdx.x) * 8;
    if (i >= n) return;
    f32x4 a = *(const f32x4*)(in + i);
    f32x4 b = *(const f32x4*)(in + i + 4);
    ushort8 o;
    o[0] = f32_to_bf16(a[0]); o[1] = f32_to_bf16(a[1]);
    o[2] = f32_to_bf16(a[2]); o[3] = f32_to_bf16(a[3]);
    o[4] = f32_to_bf16(b[0]); o[5] = f32_to_bf16(b[1]);
    o[6] = f32_to_bf16(b[2]); o[7] = f32_to_bf16(b[3]);
    *(ushort8*)(out + i) = o;
}

// ---------------- fp32 -> bf16 transpose: out[c][r] = bf16(in[r][c]) ----------------
__global__ __launch_bounds__(256) void tcvt_kernel(const float* __restrict__ in,
                                                   unsigned short* __restrict__ out,
                                                   int R, int Cn) {
    __shared__ float tl[32][33];
    const int tx = threadIdx.x & 31, ty = threadIdx.x >> 5;
    const int c0 = blockIdx.x * 32, r0 = blockIdx.y * 32;
#pragma unroll
    for (int rr = 0; rr < 4; ++rr) {
        int r = ty + rr * 8;
        tl[r][tx] = in[(size_t)(r0 + r) * Cn + c0 + tx];
    }
    __syncthreads();
#pragma unroll
    for (int rr = 0; rr < 4; ++rr) {
        int cc = ty + rr * 8;
        out[(size_t)(c0 + cc) * R + r0 + tx] = f32_to_bf16(tl[tx][cc]);
    }
}

// ---------------- bf16 MFMA GEMM, counted-vmcnt depth-2 pipeline: C = A @ Bt^T ----------------
// Triple-buffered LDS; iteration kt issues stage(kt+2); barrier waits vmcnt(4) = only the
// just-issued stage outstanding (FIFO) -> stage(kt+1) proven landed, loads span barriers.
template<bool OUT_BF16, bool SCALE_Q>
__global__ __launch_bounds__(256) void gemm_kernel(
    const unsigned short* __restrict__ A,
    const unsigned short* __restrict__ Bt,
    void* __restrict__ C, int K, int ldc)
{
    __shared__ __align__(16) unsigned short As[3][4096];
    __shared__ __align__(16) unsigned short Bs[3][4096];

    const int tid = threadIdx.x;
    const int lane = tid & 63;
    const int w = tid >> 6;
    const int wr = w >> 1, wc = w & 1;
    const int g = lane >> 4, ci = lane & 15;
    const int bx = blockIdx.x, by = blockIdx.y;
    const int soff = w * 1024 + lane * 16;       // staging byte offset (i=0)
    const int srow = soff >> 6;                  // 64B (BK=32 bf16) per row
    const int scch = (soff >> 4) & 3;

#define GSTAGE(buf, k0_) do { \
    _Pragma("unroll") for (int i_ = 0; i_ < 2; ++i_) { \
        int row_ = srow + i_ * 64; \
        gload_lds16(A  + (size_t)(by * 128 + row_) * K + (k0_) + scch * 8, \
                    (char*)As[buf] + i_ * 4096 + w * 1024); \
        gload_lds16(Bt + (size_t)(bx * 128 + row_) * K + (k0_) + scch * 8, \
                    (char*)Bs[buf] + i_ * 4096 + w * 1024); } } while (0)

    f32x4 acc[4][4];
#pragma unroll
    for (int i = 0; i < 4; ++i)
#pragma unroll
        for (int j = 0; j < 4; ++j) acc[i][j] = f32x4{0.f, 0.f, 0.f, 0.f};

    const int nk = K >> 5;
    // prologue: stage tiles 0 and 1; wait only tile 0 (vmcnt(4) leaves tile 1 in flight)
    GSTAGE(0, 0);
    GSTAGE(1, 32);
    asm volatile("s_waitcnt vmcnt(4)" ::: "memory");
    __builtin_amdgcn_sched_barrier(0);
    __builtin_amdgcn_s_barrier();
    __builtin_amdgcn_sched_barrier(0);

    for (int kt = 0; kt < nk; ++kt) {
        const int cur = kt % 3;
        if (kt + 2 < nk) GSTAGE((kt + 2) % 3, (kt + 2) << 5);   // prefetch depth 2

        bf16x8 af[4], bfr[4];
#pragma unroll
        for (int mf = 0; mf < 4; ++mf) af[mf]  = load_bf16x8(&As[cur][(wr * 64 + mf * 16 + ci) * 32 + g * 8]);
#pragma unroll
        for (int nf = 0; nf < 4; ++nf) bfr[nf] = load_bf16x8(&Bs[cur][(wc * 64 + nf * 16 + ci) * 32 + g * 8]);
        __builtin_amdgcn_s_setprio(1);
#pragma unroll
        for (int mf = 0; mf < 4; ++mf)
#pragma unroll
            for (int nf = 0; nf < 4; ++nf)
                acc[mf][nf] = __builtin_amdgcn_mfma_f32_16x16x32_bf16(af[mf], bfr[nf], acc[mf][nf], 0, 0, 0);
        __builtin_amdgcn_s_setprio(0);

        // counted barrier: drain to the just-issued stage only -> stage(kt+1) landed
        if (kt + 2 < nk) asm volatile("s_waitcnt vmcnt(4) lgkmcnt(0)" ::: "memory");
        else             asm volatile("s_waitcnt vmcnt(0) lgkmcnt(0)" ::: "memory");
        __builtin_amdgcn_sched_barrier(0);
        __builtin_amdgcn_s_barrier();
        __builtin_amdgcn_sched_barrier(0);
    }
#undef GSTAGE

#pragma unroll
    for (int mf = 0; mf < 4; ++mf)
#pragma unroll
        for (int nf = 0; nf < 4; ++nf)
#pragma unroll
            for (int r = 0; r < 4; ++r) {
                int row = by * 128 + wr * 64 + mf * 16 + g * 4 + r;
                int col = bx * 128 + wc * 64 + nf * 16 + ci;
                float v = acc[mf][nf][r];
                if (SCALE_Q && col < 1024) v *= 0.1803368801f;  // D^-0.5 * log2(e)
                if (OUT_BF16)
                    ((unsigned short*)C)[(size_t)row * ldc + col] = f32_to_bf16(v);
                else
                    ((float*)C)[(size_t)row * ldc + col] = v;
            }
}

// ---------------- causal flash attention, kv-split chunks, depth-2 pipeline ----------------
// 768 blocks: full q-tiles (qb 0..7) write attn directly; q-tiles 8..15 are split into two
// kv chunks writing unnormalized partial (O bf16, m/l fp32) for the combine kernel.
__global__ __launch_bounds__(256) void attn5_kernel(const unsigned short* __restrict__ qkv,
                                                    unsigned short* __restrict__ attn,
                                                    unsigned short* __restrict__ Obuf,
                                                    float* __restrict__ mlbuf) {
    constexpr int T = 2048, HD3 = 3072, Cc = 1024;
    __shared__ __align__(16) unsigned short Ks[3][4096];  // [64 kv][64 d], col ^= (row&7)*8
    __shared__ __align__(16) unsigned short Vt[2][4096];  // [64 d][64 kv], col ^= ((d^(d>>3))&7)*8

    const int tid = threadIdx.x;
    const int lane = tid & 63;
    const int w = tid >> 6;
    const int l31 = lane & 31;
    const int hi = lane >> 5;

    const int bx = blockIdx.x;
    const int j = bx >> 5;            // 0..23 (LPT-ordered work item)
    const int bh = bx & 31;
    const int q = qtab[j];
    const int ct = ctab[j];           // 255 = full, 0/1 = kv chunk
    const int h = bh & 15;
    const int b = bh >> 4;
    const int q0w = q * 128 + w * 32;
    const int qrow = q0w + l31;
    const size_t base = (size_t)b * T * HD3;

    const int nt_full = 2 * q + 2;
    const int ts = (ct == 1) ? (q + 1) : 0;
    const int te = (ct == 0) ? (q + 1) : nt_full;
    const int ntc = te - ts;          // >= 2 always (chunks only for q>=8)

    bf16x8 qf[4];   // B-operand: lane holds Q[qrow][t*16 + hi*8 + j] (q pre-scaled in GEMM1)
#pragma unroll
    for (int t = 0; t < 4; ++t)
        qf[t] = load_bf16x8(qkv + base + (size_t)qrow * HD3 + h * 64 + t * 16 + hi * 8);

    f32x16 acc0 = vzero16(), acc1 = vzero16();  // O^T: col=q(lane), row d = rr+8G+4hi (+32)
    float m = -3e38f, l = 0.f;

    ushort8 vA0, vA1, vB0, vB1;
#define LOADV(tile, r0, r1) do { int kv0_ = (tile) * 64; \
    int rr0_ = tid >> 3, cc0_ = tid & 7; \
    r0 = *(const ushort8*)(qkv + base + (size_t)(kv0_ + rr0_) * HD3 + 2 * Cc + h * 64 + cc0_ * 8); \
    int c1_ = 256 + tid; int rr1_ = c1_ >> 3, cc1_ = c1_ & 7; \
    r1 = *(const ushort8*)(qkv + base + (size_t)(kv0_ + rr1_) * HD3 + 2 * Cc + h * 64 + cc1_ * 8); } while (0)

#define DMAK(tile, kb) do { int kv0_ = (tile) * 64; \
    _Pragma("unroll") for (int i_ = 0; i_ < 2; ++i_) { \
        int off_ = i_ * 4096 + w * 1024 + lane * 16; \
        int row_ = off_ >> 7; \
        int csw_ = ((lane & 7) * 8) ^ ((row_ & 7) * 8); \
        gload_lds16(qkv + base + (size_t)(kv0_ + row_) * HD3 + Cc + h * 64 + csw_, \
                    (void*)(((char*)&Ks[kb][0]) + i_ * 4096 + w * 1024)); } } while (0)

#define WRITEV(vb, r0, r1) do { \
    _Pragma("unroll") for (int i_ = 0; i_ < 2; ++i_) { \
        int c_ = i_ * 256 + tid; int row_ = c_ >> 3, cc_ = c_ & 7; \
        ushort8 v_ = i_ ? r1 : r0; \
        _Pragma("unroll") for (int j_ = 0; j_ < 8; ++j_) { \
            int d_ = cc_ * 8 + j_; \
            int sw_ = ((d_ ^ (d_ >> 3)) & 7) * 8; \
            Vt[vb][d_ * 64 + (row_ ^ sw_)] = v_[j_]; } } } while (0)

    // prologue: tile ts fully staged; tile ts+1 in flight
    LOADV(ts, vA0, vA1);
    DMAK(ts, 0);
    asm volatile("s_waitcnt vmcnt(0)" ::: "memory");
    __builtin_amdgcn_sched_barrier(0);
    WRITEV(0, vA0, vA1);
    LOADV(ts + 1, vB0, vB1);
    DMAK(ts + 1, 1);
    asm volatile("s_waitcnt lgkmcnt(0)" ::: "memory");
    __builtin_amdgcn_sched_barrier(0);
    __builtin_amdgcn_s_barrier();
    __builtin_amdgcn_sched_barrier(0);

    for (int tt = 0; tt < ntc; ++tt) {
        const int t = ts + tt;
        const int kv0 = t * 64;
        const int kcur = tt % 3;
        const int vcur = tt & 1;
        const bool act = (kv0 <= q0w + 31);
        const bool pre2 = (tt + 2) < ntc;

        // 1. write V(t+1) to LDS (regs 1 tile old -> implicit vmem wait here is free)
        if (tt + 1 < ntc) {
            if (tt & 1) WRITEV(vcur ^ 1, vA0, vA1); else WRITEV(vcur ^ 1, vB0, vB1);
        }
        // 2. issue prefetch for tile t+2 (V->regs, K->LDS buf (tt+2)%3)
        if (pre2) {
            if (tt & 1) LOADV(t + 2, vB0, vB1); else LOADV(t + 2, vA0, vA1);
            DMAK(t + 2, (tt + 2) % 3);
        }

        if (act) {
            f32x16 s0 = vzero16(), s1 = vzero16();
            bf16x8 pf[4];
            const bool st1_ok = (kv0 + 32 <= q0w + 31);
            __builtin_amdgcn_s_setprio(1);
#pragma unroll
            for (int tf = 0; tf < 4; ++tf) {  // st = 0
                int row = l31;
                int idx = kcur * 4096 + row * 64 + ((tf * 16 + hi * 8) ^ ((row & 7) * 8));
                s0 = __builtin_amdgcn_mfma_f32_32x32x16_bf16(load_bf16x8(&Ks[0][idx]), qf[tf], s0, 0, 0, 0);
            }
            if (st1_ok) {
#pragma unroll
                for (int tf = 0; tf < 4; ++tf) {  // st = 1
                    int row = 32 + l31;
                    int idx = kcur * 4096 + row * 64 + ((tf * 16 + hi * 8) ^ ((row & 7) * 8));
                    s1 = __builtin_amdgcn_mfma_f32_32x32x16_bf16(load_bf16x8(&Ks[0][idx]), qf[tf], s1, 0, 0, 0);
                }
            }
            __builtin_amdgcn_s_setprio(0);
            const bool needmask = (kv0 + 63 > q0w);
            if (needmask) {
#pragma unroll
                for (int G = 0; G < 4; ++G)
#pragma unroll
                    for (int rr = 0; rr < 4; ++rr) {
                        int kvb = kv0 + 8 * G + 4 * hi + rr;  // kv of C-reg (crow formula, HW-verified)
                        s0[G * 4 + rr] = (kvb      <= qrow) ? s0[G * 4 + rr] : -3e38f;
                        s1[G * 4 + rr] = (kvb + 32 <= qrow) ? s1[G * 4 + rr] : -3e38f;
                    }
            }
            float pmax = tmax32(s0, s1);
            pmax = fmaxf(pmax, __shfl_xor(pmax, 32));   // HW-verified exchange
            // defer-max (T13): skip O/l rescale while pmax - m <= 11.5 (log2 domain)
            if (!__all(pmax - m <= 11.5f)) {
                float mnew = fmaxf(m, pmax);
                float alpha = exp2f(m - mnew);
                m = mnew;
                l *= alpha;
#pragma unroll
                for (int i = 0; i < 16; ++i) { acc0[i] *= alpha; acc1[i] *= alpha; }
            }
#pragma unroll
            for (int i = 0; i < 16; ++i) {
                s0[i] = exp2f(s0[i] - m);
                s1[i] = exp2f(s1[i] - m);
            }

            // P -> B-fragments (cvt_pk + lane<->lane+32 exchange, HW-verified construction)
            unsigned pk0[4][2], pk1[4][2];
#pragma unroll
            for (int G = 0; G < 4; ++G) {
                pk0[G][0] = cvt_pk_bf16(s0[G * 4 + 0], s0[G * 4 + 1]);
                pk0[G][1] = cvt_pk_bf16(s0[G * 4 + 2], s0[G * 4 + 3]);
                pk1[G][0] = cvt_pk_bf16(s1[G * 4 + 0], s1[G * 4 + 1]);
                pk1[G][1] = cvt_pk_bf16(s1[G * 4 + 2], s1[G * 4 + 3]);
            }
#pragma unroll
            for (int tf = 0; tf < 4; ++tf) {
                const int kb = tf & 1;
                unsigned sA0, sA1, sB0, sB1;
                if (tf < 2) { sA0 = pk0[2 * kb][0]; sA1 = pk0[2 * kb][1]; sB0 = pk0[2 * kb + 1][0]; sB1 = pk0[2 * kb + 1][1]; }
                else        { sA0 = pk1[2 * kb][0]; sA1 = pk1[2 * kb][1]; sB0 = pk1[2 * kb + 1][0]; sB1 = pk1[2 * kb + 1][1]; }
                unsigned sd0 = hi ? sA0 : sB0, sd1 = hi ? sA1 : sB1;
                unsigned rc0 = (unsigned)__shfl_xor((int)sd0, 32);
                unsigned rc1 = (unsigned)__shfl_xor((int)sd1, 32);
                uint4v u;
                u[0] = hi ? rc0 : sA0;  u[1] = hi ? rc1 : sA1;   // k = hi*8 + 0..3
                u[2] = hi ? sB0 : rc0;  u[3] = hi ? sB1 : rc1;   // k = hi*8 + 4..7
                pf[tf] = __builtin_bit_cast(bf16x8, u);
            }

            __builtin_amdgcn_s_setprio(1);
#pragma unroll
            for (int tf = 0; tf < 4; ++tf) {
                {
                    int d = l31, sw = ((d ^ (d >> 3)) & 7) * 8;
                    bf16x8 vf = load_bf16x8(&Vt[vcur][d * 64 + ((tf * 16 + hi * 8) ^ sw)]);
                    acc0 = __builtin_amdgcn_mfma_f32_32x32x16_bf16(vf, pf[tf], acc0, 0, 0, 0);
                }
                {
                    int d = 32 + l31, sw = ((d ^ (d >> 3)) & 7) * 8;
                    bf16x8 vf = load_bf16x8(&Vt[vcur][d * 64 + ((tf * 16 + hi * 8) ^ sw)]);
                    acc1 = __builtin_amdgcn_mfma_f32_32x32x16_bf16(vf, pf[tf], acc1, 0, 0, 0);
                }
            }
            __builtin_amdgcn_s_setprio(0);

            // row-sum + l update off the PV critical path
            float rsum = tsum32(s0, s1);
            l += rsum + __shfl_xor(rsum, 32);
        }

        // counted-vmcnt barrier: guarantee K(t+1) landed, keep t+2 prefetch in flight
        if (pre2) asm volatile("s_waitcnt vmcnt(4) lgkmcnt(0)" ::: "memory");
        else      asm volatile("s_waitcnt vmcnt(0) lgkmcnt(0)" ::: "memory");
        __builtin_amdgcn_sched_barrier(0);
        __builtin_amdgcn_s_barrier();
        __builtin_amdgcn_sched_barrier(0);
    }

    if (ct == 255) {
        // full q-tile: normalize and write attn
        const float invl = 1.0f / l;
        const size_t ob = (size_t)b * T * Cc + (size_t)qrow * Cc + h * 64;
#pragma unroll
        for (int G = 0; G < 4; ++G) {
            ushort4v o0, o1;
#pragma unroll
            for (int rr = 0; rr < 4; ++rr) {
                o0[rr] = f32_to_bf16(acc0[G * 4 + rr] * invl);
                o1[rr] = f32_to_bf16(acc1[G * 4 + rr] * invl);
            }
            int d0 = 8 * G + 4 * hi;
            *(ushort4v*)(attn + ob + d0) = o0;
            *(ushort4v*)(attn + ob + 32 + d0) = o1;
        }
    } else {
        // chunk: write unnormalized partial O (bf16) + m,l (fp32)
        const int slot = bh * 16 + (q - 8) * 2 + ct;
        const int qlocal = w * 32 + l31;
        unsigned short* op = Obuf + (size_t)slot * 8192 + qlocal * 64;
#pragma unroll
        for (int G = 0; G < 4; ++G) {
            ushort4v o0, o1;
#pragma unroll
            for (int rr = 0; rr < 4; ++rr) {
                o0[rr] = f32_to_bf16(acc0[G * 4 + rr]);
                o1[rr] = f32_to_bf16(acc1[G * 4 + rr]);
            }
            int d0 = 8 * G + 4 * hi;
            *(ushort4v*)(op + d0) = o0;
            *(ushort4v*)(op + 32 + d0) = o1;
        }
        if (hi == 0) {
            mlbuf[slot * 256 + qlocal * 2]     = m;
            mlbuf[slot * 256 + qlocal * 2 + 1] = l;
        }
    }
#undef LOADV
#undef DMAK
#undef WRITEV
}

// ---------------- combine: merge the two kv-chunks of each split q-tile ----------------
__global__ __launch_bounds__(256) void combine_kernel(const unsigned short* __restrict__ Obuf,
                                                      const float* __restrict__ mlbuf,
                                                      unsigned short* __restrict__ attn) {
    constexpr int T = 2048, Cc = 1024;
    const int ss = blockIdx.x;            // 0..255: (bh, qq)
    const int bh = ss >> 3, qq = 8 + (ss & 7);
    const int b = bh >> 4, h = bh & 15;
    const int slot0 = bh * 16 + (qq - 8) * 2;
    const int tid = threadIdx.x;
    const int qlocal = tid >> 1, dh = (tid & 1) * 32;

    const float* ml0 = mlbuf + (size_t)slot0 * 256 + qlocal * 2;
    const float* ml1 = ml0 + 256;
    float m0 = ml0[0], l0 = ml0[1], m1 = ml1[0], l1 = ml1[1];
    float M = fmaxf(m0, m1);
    float w0 = exp2f(m0 - M), w1 = exp2f(m1 - M);
    float inv = 1.f / (w0 * l0 + w1 * l1);

    const unsigned short* p0 = Obuf + (size_t)slot0 * 8192 + qlocal * 64 + dh;
    const unsigned short* p1 = p0 + 8192;
    unsigned short* po = attn + (size_t)b * T * Cc + (size_t)(qq * 128 + qlocal) * Cc + h * 64 + dh;
#pragma unroll
    for (int i = 0; i < 4; ++i) {
        ushort8 a = *(const ushort8*)(p0 + i * 8);
        ushort8 c = *(const ushort8*)(p1 + i * 8);
        ushort8 o;
#pragma unroll
        for (int k = 0; k < 8; ++k)
            o[k] = f32_to_bf16((w0 * bf16_to_f32(a[k]) + w1 * bf16_to_f32(c[k])) * inv);
        *(ushort8*)(po + i * 8) = o;
    }
}

extern "C" void kernel_launch(void* const* d_in, const int* in_sizes, int n_in,
                              void* d_out, int out_size, void* d_ws, size_t ws_size,
                              hipStream_t stream) {
    const float* x     = (const float*)d_in[0];
    // d_in[1] = mask (tril -> causal predicate), unused
    const float* w_qkv = (const float*)d_in[2];
    const float* w_out = (const float*)d_in[3];
    // d_in[4] = charge_w: provably no-op, unused
    float* out = (float*)d_out;

    // workspace (bf16 elements)
    unsigned short* xb     = (unsigned short*)d_ws;
    unsigned short* wqkvT  = xb + 4194304;        // [3072][1024]
    unsigned short* woutT  = wqkvT + 3145728;     // [1024][1024]
    unsigned short* qkv    = woutT + 1048576;     // [4096][3072]
    unsigned short* attn   = qkv + 12582912;      // [4096][1024]
    // partials alias regions that are dead after GEMM1:
    unsigned short* Obuf   = xb;                  // 512 slots x 128 x 64 bf16 = 8 MB
    float*          mlbuf  = (float*)wqkvT;       // 512 slots x 128 x 2 fp32 = 512 KB

    cvt_kernel<<<2048, 256, 0, stream>>>(x, xb, 4194304);
    tcvt_kernel<<<dim3(96, 32), 256, 0, stream>>>(w_qkv, wqkvT, 1024, 3072);
    tcvt_kernel<<<dim3(32, 32), 256, 0, stream>>>(w_out, woutT, 1024, 1024);

    // qkv = xb @ w_qkv (M=4096, N=3072, K=1024), bf16 out, q-columns pre-scaled
    gemm_kernel<true, true><<<dim3(24, 32), 256, 0, stream>>>(xb, wqkvT, (void*)qkv, 1024, 3072);

    // causal attention: 768 LPT-ordered blocks (full tiles + kv-split chunks)
    attn5_kernel<<<768, 256, 0, stream>>>(qkv, attn, Obuf, mlbuf);
    combine_kernel<<<256, 256, 0, stream>>>(Obuf, mlbuf, attn);

    // out = attn @ w_out (M=4096, N=1024, K=1024), fp32 out
    gemm_kernel<false, false><<<dim3(8, 32), 256, 0, stream>>>(attn, woutT, (void*)out, 1024, 1024);
}